// Round 3
// baseline (549.849 us; speedup 1.0000x reference)
//
#include <hip/hip_runtime.h>
#include <hip/hip_bf16.h>
#include <math.h>

#define N_NODES 50000
#define N_EDGES 1600000
#define IN_CH 128
#define OUT_SZ 64

#define NODE_BLOCKS 3125
#define HIST_BLOCKS 512

// monotone f32 -> u32 mapping for atomicMax on floats
__device__ __forceinline__ unsigned fenc(float x) {
    unsigned u = __float_as_uint(x);
    return (u & 0x80000000u) ? ~u : (u | 0x80000000u);
}
__device__ __forceinline__ float fdec(unsigned u) {
    return __uint_as_float((u & 0x80000000u) ? (u & 0x7fffffffu) : ~u);
}

// ---------------- K0: zero counters + softmax scalars ----------------
__global__ __launch_bounds__(256) void k_zero(unsigned* pmax1, unsigned* pmax2,
                                              float* psum, unsigned* counts) {
    int i = blockIdx.x * 256 + threadIdx.x;
    if (i < N_NODES) counts[i] = 0u;
    if (i == 0) { *pmax1 = 0u; *pmax2 = 0u; *psum = 0.0f; }
}

// ---------------- K1: fused per-node linears + src histogram ----------------
// blocks [0, HIST_BLOCKS): histogram of src
// blocks [HIST_BLOCKS, HIST_BLOCKS+NODE_BLOCKS): node linears, 1 wave = 4 nodes
__global__ __launch_bounds__(256) void k_nodehist(
    const float* __restrict__ seq, const float* __restrict__ Wseq,
    const float* __restrict__ Wres, const float* __restrict__ wf1,
    const float* __restrict__ bf1, const float* __restrict__ wf2,
    const float* __restrict__ bf2, const float* __restrict__ bias,
    const float* __restrict__ bres, const int* __restrict__ ei,
    unsigned* __restrict__ counts, unsigned* pmax1, unsigned* pmax2,
    __hip_bfloat16* __restrict__ sftsh, float* __restrict__ f1,
    float* __restrict__ f2, float* __restrict__ out)
{
    __shared__ float2 Wp[IN_CH * 64];   // (w_seq[c], w_res[c]) at [i*64 + (c^(i&31))]
    const int t = threadIdx.x;

    if (blockIdx.x < HIST_BLOCKS) {     // histogram part
        int tid = blockIdx.x * 256 + t;
        int stride = HIST_BLOCKS * 256;
        for (int e = tid; e < N_EDGES; e += stride)
            atomicAdd(&counts[ei[e]], 1u);
        return;
    }

    // node part
#pragma unroll
    for (int k = 0; k < 32; ++k) {
        int idx = t + k * 256;          // 8192 = 64 ch * 128 i
        int c = idx >> 7;               // 0..63
        int i = idx & 127;              // consecutive across threads -> coalesced reads
        float ws = Wseq[c * IN_CH + i];
        float wr = Wres[c * IN_CH + i];
        Wp[i * 64 + (c ^ (i & 31))] = make_float2(ws, wr);
    }
    __syncthreads();

    const int lane = t & 63;
    const int wv = t >> 6;
    const int n0 = ((int)(blockIdx.x - HIST_BLOCKS) * 4 + wv) * 4;
    if (n0 >= N_NODES) return;
    const float* s0p = seq + (size_t)n0 * IN_CH;

    float a00 = 0.f, a01 = 0.f, a10 = 0.f, a11 = 0.f;
    float a20 = 0.f, a21 = 0.f, a30 = 0.f, a31 = 0.f;
#pragma unroll 4
    for (int i0 = 0; i0 < IN_CH; i0 += 4) {
        float4 s0 = *(const float4*)(s0p + i0);
        float4 s1 = *(const float4*)(s0p + IN_CH + i0);
        float4 s2 = *(const float4*)(s0p + 2 * IN_CH + i0);
        float4 s3 = *(const float4*)(s0p + 3 * IN_CH + i0);
#pragma unroll
        for (int k = 0; k < 4; ++k) {
            int i = i0 + k;
            float2 w = Wp[i * 64 + (lane ^ (i & 31))];
            float e0 = (k == 0) ? s0.x : (k == 1) ? s0.y : (k == 2) ? s0.z : s0.w;
            float e1 = (k == 0) ? s1.x : (k == 1) ? s1.y : (k == 2) ? s1.z : s1.w;
            float e2 = (k == 0) ? s2.x : (k == 1) ? s2.y : (k == 2) ? s2.z : s2.w;
            float e3 = (k == 0) ? s3.x : (k == 1) ? s3.y : (k == 2) ? s3.z : s3.w;
            a00 = fmaf(e0, w.x, a00); a01 = fmaf(e0, w.y, a01);
            a10 = fmaf(e1, w.x, a10); a11 = fmaf(e1, w.y, a11);
            a20 = fmaf(e2, w.x, a20); a21 = fmaf(e2, w.y, a21);
            a30 = fmaf(e3, w.x, a30); a31 = fmaf(e3, w.y, a31);
        }
    }

    float wl1 = wf1[lane], wl2 = wf2[lane];
    float r10 = a00 * wl1, r20 = a00 * wl2;
    float r11 = a10 * wl1, r21 = a10 * wl2;
    float r12 = a20 * wl1, r22 = a20 * wl2;
    float r13 = a30 * wl1, r23 = a30 * wl2;
#pragma unroll
    for (int off = 32; off; off >>= 1) {
        r10 += __shfl_xor(r10, off); r20 += __shfl_xor(r20, off);
        r11 += __shfl_xor(r11, off); r21 += __shfl_xor(r21, off);
        r12 += __shfl_xor(r12, off); r22 += __shfl_xor(r22, off);
        r13 += __shfl_xor(r13, off); r23 += __shfl_xor(r23, off);
    }

    float bb = bias[lane] + bres[lane];
    size_t o = (size_t)n0 * 64 + lane;
    sftsh[o]       = __float2bfloat16(a00);  out[o]       = a01 + bb;
    sftsh[o + 64]  = __float2bfloat16(a10);  out[o + 64]  = a11 + bb;
    sftsh[o + 128] = __float2bfloat16(a20);  out[o + 128] = a21 + bb;
    sftsh[o + 192] = __float2bfloat16(a30);  out[o + 192] = a31 + bb;

    if (lane == 0) {
        float B1 = bf1[0], B2 = bf2[0];
        float F10 = r10 + B1, F11 = r11 + B1, F12 = r12 + B1, F13 = r13 + B1;
        float F20 = r20 + B2, F21 = r21 + B2, F22 = r22 + B2, F23 = r23 + B2;
        f1[n0] = F10; f1[n0 + 1] = F11; f1[n0 + 2] = F12; f1[n0 + 3] = F13;
        f2[n0] = F20; f2[n0 + 1] = F21; f2[n0 + 2] = F22; f2[n0 + 3] = F23;
        atomicMax(pmax1, fenc(fmaxf(fmaxf(F10, F11), fmaxf(F12, F13))));
        atomicMax(pmax2, fenc(fmaxf(fmaxf(F20, F21), fmaxf(F22, F23))));
    }
}

// ---------------- K2: single-block scan (counts -> offs, cursor) ----------------
#define SCAN_T 1024
#define SCAN_PER 49   // 1024*49 = 50176 >= 50000
__global__ __launch_bounds__(SCAN_T) void k_scan(
    const unsigned* __restrict__ counts, unsigned* __restrict__ offs,
    unsigned* __restrict__ cursor)
{
    __shared__ unsigned bs[SCAN_T];
    const int t = threadIdx.x;
    unsigned loc[SCAN_PER];
    unsigned s = 0;
    const int base = t * SCAN_PER;
#pragma unroll
    for (int k = 0; k < SCAN_PER; ++k) {
        int i = base + k;
        unsigned c = (i < N_NODES) ? counts[i] : 0u;
        loc[k] = s;
        s += c;
    }
    bs[t] = s;
    __syncthreads();
    for (int off = 1; off < SCAN_T; off <<= 1) {
        unsigned v = (t >= off) ? bs[t - off] : 0u;
        __syncthreads();
        bs[t] += v;
        __syncthreads();
    }
    unsigned prev = t ? bs[t - 1] : 0u;
#pragma unroll
    for (int k = 0; k < SCAN_PER; ++k) {
        int i = base + k;
        if (i < N_NODES) {
            unsigned o = prev + loc[k];
            offs[i] = o;
            cursor[i] = o;
        }
    }
    if (t == SCAN_T - 1) offs[N_NODES] = bs[SCAN_T - 1];
}

// ---------------- K3: place dst (u16) into src-sorted order + sum exp ----------------
__global__ __launch_bounds__(256) void k_placesum(
    const int* __restrict__ ei, const float* __restrict__ f1,
    const float* __restrict__ f2, const unsigned* __restrict__ pmax1,
    const unsigned* __restrict__ pmax2, unsigned* __restrict__ cursor,
    unsigned short* __restrict__ sDst, float* psum)
{
    float M = fdec(*pmax1) + fdec(*pmax2);
    M = (M > 0.f) ? M : 0.01f * M;          // LRelu of upper bound: valid shift constant
    int tid = blockIdx.x * 256 + threadIdx.x;
    int stride = gridDim.x * 256;
    float ls = 0.f;
    for (int e = tid; e < N_EDGES; e += stride) {
        int src = ei[e];
        int dst = ei[N_EDGES + e];
        float x = f1[src] + f2[dst];
        x = (x > 0.f) ? x : 0.01f * x;
        ls += __expf(x - M);
        unsigned pos = atomicAdd(&cursor[src], 1u);
        sDst[pos] = (unsigned short)dst;
    }
#pragma unroll
    for (int off = 32; off; off >>= 1) ls += __shfl_xor(ls, off);
    __shared__ float red[4];
    if ((threadIdx.x & 63) == 0) red[threadIdx.x >> 6] = ls;
    __syncthreads();
    if (threadIdx.x == 0) {
        ls = red[0] + red[1] + red[2] + red[3];
        unsafeAtomicAdd(psum, ls);
    }
}

// ---------------- K4: per-node accumulate + ELU, 8-deep pipelined gathers ----------------
// one wave per node; lane = channel
__global__ __launch_bounds__(256) void k_acc(
    const unsigned* __restrict__ offs, const unsigned short* __restrict__ sDst,
    const float* __restrict__ f1, const float* __restrict__ f2,
    const __hip_bfloat16* __restrict__ sftsh, const unsigned* __restrict__ pmax1,
    const unsigned* __restrict__ pmax2, const float* __restrict__ psum,
    float* __restrict__ out)
{
    const int lane = threadIdx.x & 63;
    const int n = (blockIdx.x * 256 + threadIdx.x) >> 6;
    if (n >= N_NODES) return;
    float M = fdec(*pmax1) + fdec(*pmax2);
    M = (M > 0.f) ? M : 0.01f * M;
    const float inv = 1.0f / (*psum);
    const unsigned b = offs[n];
    const unsigned e = offs[n + 1];
    const float f1n = f1[n];

    float acc = 0.f;
    for (unsigned e0 = b; e0 < e; e0 += 64) {
        const int cnt = (int)min(64u, e - e0);
        int dst = 0;
        float coef = 0.f;               // lanes >= cnt contribute 0
        if (lane < cnt) {
            dst = (int)sDst[e0 + lane];
            float x = f1n + f2[dst];
            x = (x > 0.f) ? x : 0.01f * x;
            coef = __expf(x - M) * inv;
        }
        const int nb = (cnt + 7) & ~7;  // ragged tail handled by coef==0 lanes
        for (int j = 0; j < nb; j += 8) {
            int d0 = __shfl(dst, j);     float c0 = __shfl(coef, j);
            int d1 = __shfl(dst, j + 1); float c1 = __shfl(coef, j + 1);
            int d2 = __shfl(dst, j + 2); float c2 = __shfl(coef, j + 2);
            int d3 = __shfl(dst, j + 3); float c3 = __shfl(coef, j + 3);
            int d4 = __shfl(dst, j + 4); float c4 = __shfl(coef, j + 4);
            int d5 = __shfl(dst, j + 5); float c5 = __shfl(coef, j + 5);
            int d6 = __shfl(dst, j + 6); float c6 = __shfl(coef, j + 6);
            int d7 = __shfl(dst, j + 7); float c7 = __shfl(coef, j + 7);
            float v0 = __bfloat162float(sftsh[(size_t)d0 * 64 + lane]);
            float v1 = __bfloat162float(sftsh[(size_t)d1 * 64 + lane]);
            float v2 = __bfloat162float(sftsh[(size_t)d2 * 64 + lane]);
            float v3 = __bfloat162float(sftsh[(size_t)d3 * 64 + lane]);
            float v4 = __bfloat162float(sftsh[(size_t)d4 * 64 + lane]);
            float v5 = __bfloat162float(sftsh[(size_t)d5 * 64 + lane]);
            float v6 = __bfloat162float(sftsh[(size_t)d6 * 64 + lane]);
            float v7 = __bfloat162float(sftsh[(size_t)d7 * 64 + lane]);
            acc = fmaf(c0, v0, acc); acc = fmaf(c1, v1, acc);
            acc = fmaf(c2, v2, acc); acc = fmaf(c3, v3, acc);
            acc = fmaf(c4, v4, acc); acc = fmaf(c5, v5, acc);
            acc = fmaf(c6, v6, acc); acc = fmaf(c7, v7, acc);
        }
    }
    const size_t idx = (size_t)n * 64 + lane;
    float x = out[idx] + acc;
    out[idx] = (x > 0.f) ? x : expm1f(x);
}

extern "C" void kernel_launch(void* const* d_in, const int* in_sizes, int n_in,
                              void* d_out, int out_size, void* d_ws, size_t ws_size,
                              hipStream_t stream) {
    const float* seq  = (const float*)d_in[0];
    const int*   ei   = (const int*)d_in[1];
    const float* Wseq = (const float*)d_in[2];
    const float* wf1  = (const float*)d_in[3];
    const float* bf1  = (const float*)d_in[4];
    const float* wf2  = (const float*)d_in[5];
    const float* bf2  = (const float*)d_in[6];
    const float* bias = (const float*)d_in[7];
    const float* Wres = (const float*)d_in[8];
    const float* bres = (const float*)d_in[9];
    float* out = (float*)d_out;

    // ws layout
    unsigned* pmax1       = (unsigned*)d_ws;
    unsigned* pmax2       = (unsigned*)d_ws + 1;
    float*    psum        = (float*)d_ws + 2;
    unsigned* counts      = (unsigned*)d_ws + 16;
    unsigned* offs        = counts + N_NODES;                      // N_NODES+1
    unsigned* cursor      = offs + N_NODES + 1;
    unsigned short* sDst  = (unsigned short*)(cursor + N_NODES);   // N_EDGES u16
    __hip_bfloat16* sftsh = (__hip_bfloat16*)(sDst + N_EDGES);     // N*64 bf16
    float*    f1          = (float*)(sftsh + (size_t)N_NODES * 64);
    float*    f2          = f1 + N_NODES;
    // total ~11 MB

    k_zero<<<196, 256, 0, stream>>>(pmax1, pmax2, psum, counts);
    k_nodehist<<<NODE_BLOCKS + HIST_BLOCKS, 256, 0, stream>>>(
        seq, Wseq, Wres, wf1, bf1, wf2, bf2, bias, bres, ei,
        counts, pmax1, pmax2, sftsh, f1, f2, out);
    k_scan<<<1, SCAN_T, 0, stream>>>(counts, offs, cursor);
    k_placesum<<<2048, 256, 0, stream>>>(ei, f1, f2, pmax1, pmax2, cursor, sDst, psum);
    k_acc<<<12500, 256, 0, stream>>>(offs, sDst, f1, f2, sftsh, pmax1, pmax2, psum, out);
}

// Round 4
// 376.221 us; speedup vs baseline: 1.4615x; 1.4615x over previous
//
#include <hip/hip_runtime.h>
#include <hip/hip_bf16.h>
#include <math.h>

#define N_NODES 50000
#define N_EDGES 1600000
#define IN_CH 128
#define OUT_SZ 64

// monotone f32 -> u32 mapping for atomicMax on floats
__device__ __forceinline__ unsigned fenc(float x) {
    unsigned u = __float_as_uint(x);
    return (u & 0x80000000u) ? ~u : (u | 0x80000000u);
}
__device__ __forceinline__ float fdec(unsigned u) {
    return __uint_as_float((u & 0x80000000u) ? (u & 0x7fffffffu) : ~u);
}

// ---------------- K0: zero counters + softmax scalars ----------------
__global__ __launch_bounds__(256) void k_zero(unsigned* pmax1, unsigned* pmax2,
                                              float* psum, unsigned* counts) {
    int i = blockIdx.x * 256 + threadIdx.x;
    if (i < N_NODES) counts[i] = 0u;
    if (i == 0) { *pmax1 = 0u; *pmax2 = 0u; *psum = 0.0f; }
}

// ---------------- K0b: src histogram ----------------
__global__ __launch_bounds__(256) void k_hist(const int* __restrict__ ei,
                                              unsigned* __restrict__ counts) {
    int tid = blockIdx.x * 256 + threadIdx.x;
    int stride = gridDim.x * 256;
    for (int e = tid; e < N_EDGES; e += stride)
        atomicAdd(&counts[ei[e]], 1u);
}

// ---------------- K1: per-node linears (R1/R2 proven structure) ----------------
// one wave handles 4 nodes; lane = output channel (0..63)
// W staged in LDS as [i][c ^ (i&31)], c in [0,128): c<64 -> W_seq, c>=64 -> W_res
__global__ __launch_bounds__(256) void k_node(
    const float* __restrict__ seq, const float* __restrict__ Wseq,
    const float* __restrict__ Wres, const float* __restrict__ wf1,
    const float* __restrict__ bf1, const float* __restrict__ wf2,
    const float* __restrict__ bf2, const float* __restrict__ bias,
    const float* __restrict__ bres,
    __hip_bfloat16* __restrict__ sftsh, float* __restrict__ f1,
    float* __restrict__ f2, unsigned* pmax1, unsigned* pmax2,
    float* __restrict__ out)
{
    __shared__ float W[IN_CH * 128];
    const int t = threadIdx.x;
#pragma unroll
    for (int k = 0; k < 64; ++k) {
        int idx = t + k * 256;          // 16384 = 128 ch * 128 i
        int c = idx >> 7;
        int i = idx & 127;
        float v = (c < 64) ? Wseq[c * IN_CH + i] : Wres[(c - 64) * IN_CH + i];
        W[i * 128 + (c ^ (i & 31))] = v;
    }
    __syncthreads();

    const int lane = t & 63;
    const int wv = t >> 6;
    const int n0 = (blockIdx.x * 4 + wv) * 4;    // 3125*16 = 50000 exactly, no early exit
    const float* s0p = seq + (size_t)n0 * IN_CH;

    float a00 = 0.f, a01 = 0.f, a10 = 0.f, a11 = 0.f;
    float a20 = 0.f, a21 = 0.f, a30 = 0.f, a31 = 0.f;
#pragma unroll 4
    for (int i = 0; i < IN_CH; ++i) {
        int sw = i * 128 + (lane ^ (i & 31));
        float w1 = W[sw];
        float w2 = W[sw + 64];
        float s0 = s0p[i];
        float s1 = s0p[IN_CH + i];
        float s2 = s0p[2 * IN_CH + i];
        float s3 = s0p[3 * IN_CH + i];
        a00 = fmaf(s0, w1, a00); a01 = fmaf(s0, w2, a01);
        a10 = fmaf(s1, w1, a10); a11 = fmaf(s1, w2, a11);
        a20 = fmaf(s2, w1, a20); a21 = fmaf(s2, w2, a21);
        a30 = fmaf(s3, w1, a30); a31 = fmaf(s3, w2, a31);
    }

    // f1/f2 dot-products over the 64 channels (lanes)
    float wl1 = wf1[lane], wl2 = wf2[lane];
    float r10 = a00 * wl1, r20 = a00 * wl2;
    float r11 = a10 * wl1, r21 = a10 * wl2;
    float r12 = a20 * wl1, r22 = a20 * wl2;
    float r13 = a30 * wl1, r23 = a30 * wl2;
#pragma unroll
    for (int off = 32; off; off >>= 1) {
        r10 += __shfl_xor(r10, off); r20 += __shfl_xor(r20, off);
        r11 += __shfl_xor(r11, off); r21 += __shfl_xor(r21, off);
        r12 += __shfl_xor(r12, off); r22 += __shfl_xor(r22, off);
        r13 += __shfl_xor(r13, off); r23 += __shfl_xor(r23, off);
    }

    float bb = bias[lane] + bres[lane];
    size_t o = (size_t)n0 * 64 + lane;
    sftsh[o]       = __float2bfloat16(a00);  out[o]       = a01 + bb;
    sftsh[o + 64]  = __float2bfloat16(a10);  out[o + 64]  = a11 + bb;
    sftsh[o + 128] = __float2bfloat16(a20);  out[o + 128] = a21 + bb;
    sftsh[o + 192] = __float2bfloat16(a30);  out[o + 192] = a31 + bb;

    // block-level max of f1/f2 (2 atomics per block, not per wave)
    __syncthreads();                    // everyone done reading W; reuse as scratch
    if (lane == 0) {
        float B1 = bf1[0], B2 = bf2[0];
        float F10 = r10 + B1, F11 = r11 + B1, F12 = r12 + B1, F13 = r13 + B1;
        float F20 = r20 + B2, F21 = r21 + B2, F22 = r22 + B2, F23 = r23 + B2;
        f1[n0] = F10; f1[n0 + 1] = F11; f1[n0 + 2] = F12; f1[n0 + 3] = F13;
        f2[n0] = F20; f2[n0 + 1] = F21; f2[n0 + 2] = F22; f2[n0 + 3] = F23;
        W[wv]     = fmaxf(fmaxf(F10, F11), fmaxf(F12, F13));
        W[4 + wv] = fmaxf(fmaxf(F20, F21), fmaxf(F22, F23));
    }
    __syncthreads();
    if (t == 0) {
        atomicMax(pmax1, fenc(fmaxf(fmaxf(W[0], W[1]), fmaxf(W[2], W[3]))));
        atomicMax(pmax2, fenc(fmaxf(fmaxf(W[4], W[5]), fmaxf(W[6], W[7]))));
    }
}

// ---------------- K2: single-block scan (counts -> offs, cursor) ----------------
#define SCAN_T 1024
#define SCAN_PER 49   // 1024*49 = 50176 >= 50000
__global__ __launch_bounds__(SCAN_T) void k_scan(
    const unsigned* __restrict__ counts, unsigned* __restrict__ offs,
    unsigned* __restrict__ cursor)
{
    __shared__ unsigned bs[SCAN_T];
    const int t = threadIdx.x;
    unsigned loc[SCAN_PER];
    unsigned s = 0;
    const int base = t * SCAN_PER;
#pragma unroll
    for (int k = 0; k < SCAN_PER; ++k) {
        int i = base + k;
        unsigned c = (i < N_NODES) ? counts[i] : 0u;
        loc[k] = s;
        s += c;
    }
    bs[t] = s;
    __syncthreads();
    for (int off = 1; off < SCAN_T; off <<= 1) {
        unsigned v = (t >= off) ? bs[t - off] : 0u;
        __syncthreads();
        bs[t] += v;
        __syncthreads();
    }
    unsigned prev = t ? bs[t - 1] : 0u;
#pragma unroll
    for (int k = 0; k < SCAN_PER; ++k) {
        int i = base + k;
        if (i < N_NODES) {
            unsigned o = prev + loc[k];
            offs[i] = o;
            cursor[i] = o;
        }
    }
    if (t == SCAN_T - 1) offs[N_NODES] = bs[SCAN_T - 1];
}

// ---------------- K3: place dst (u16) into src-sorted order + sum exp ----------------
__global__ __launch_bounds__(256) void k_placesum(
    const int* __restrict__ ei, const float* __restrict__ f1,
    const float* __restrict__ f2, const unsigned* __restrict__ pmax1,
    const unsigned* __restrict__ pmax2, unsigned* __restrict__ cursor,
    unsigned short* __restrict__ sDst, float* psum)
{
    float M = fdec(*pmax1) + fdec(*pmax2);
    M = (M > 0.f) ? M : 0.01f * M;          // LRelu of upper bound: valid shift constant
    int tid = blockIdx.x * 256 + threadIdx.x;
    int stride = gridDim.x * 256;
    float ls = 0.f;
    for (int e = tid; e < N_EDGES; e += stride) {
        int src = ei[e];
        int dst = ei[N_EDGES + e];
        float x = f1[src] + f2[dst];
        x = (x > 0.f) ? x : 0.01f * x;
        ls += __expf(x - M);
        unsigned pos = atomicAdd(&cursor[src], 1u);
        sDst[pos] = (unsigned short)dst;
    }
#pragma unroll
    for (int off = 32; off; off >>= 1) ls += __shfl_xor(ls, off);
    __shared__ float red[4];
    if ((threadIdx.x & 63) == 0) red[threadIdx.x >> 6] = ls;
    __syncthreads();
    if (threadIdx.x == 0) {
        ls = red[0] + red[1] + red[2] + red[3];
        unsafeAtomicAdd(psum, ls);
    }
}

// ---------------- K4: per-node accumulate + ELU, 8-deep pipelined gathers ----------------
// one wave per node; lane = channel
__global__ __launch_bounds__(256) void k_acc(
    const unsigned* __restrict__ offs, const unsigned short* __restrict__ sDst,
    const float* __restrict__ f1, const float* __restrict__ f2,
    const __hip_bfloat16* __restrict__ sftsh, const unsigned* __restrict__ pmax1,
    const unsigned* __restrict__ pmax2, const float* __restrict__ psum,
    float* __restrict__ out)
{
    const int lane = threadIdx.x & 63;
    const int n = (blockIdx.x * 256 + threadIdx.x) >> 6;
    if (n >= N_NODES) return;
    float M = fdec(*pmax1) + fdec(*pmax2);
    M = (M > 0.f) ? M : 0.01f * M;
    const float inv = 1.0f / (*psum);
    const unsigned b = offs[n];
    const unsigned e = offs[n + 1];
    const float f1n = f1[n];

    float acc = 0.f;
    for (unsigned e0 = b; e0 < e; e0 += 64) {
        const int cnt = (int)min(64u, e - e0);
        int dst = 0;
        float coef = 0.f;               // lanes >= cnt contribute 0
        if (lane < cnt) {
            dst = (int)sDst[e0 + lane];
            float x = f1n + f2[dst];
            x = (x > 0.f) ? x : 0.01f * x;
            coef = __expf(x - M) * inv;
        }
        const int nb = (cnt + 7) & ~7;  // ragged tail handled by coef==0 lanes
        for (int j = 0; j < nb; j += 8) {
            int d0 = __shfl(dst, j);     float c0 = __shfl(coef, j);
            int d1 = __shfl(dst, j + 1); float c1 = __shfl(coef, j + 1);
            int d2 = __shfl(dst, j + 2); float c2 = __shfl(coef, j + 2);
            int d3 = __shfl(dst, j + 3); float c3 = __shfl(coef, j + 3);
            int d4 = __shfl(dst, j + 4); float c4 = __shfl(coef, j + 4);
            int d5 = __shfl(dst, j + 5); float c5 = __shfl(coef, j + 5);
            int d6 = __shfl(dst, j + 6); float c6 = __shfl(coef, j + 6);
            int d7 = __shfl(dst, j + 7); float c7 = __shfl(coef, j + 7);
            float v0 = __bfloat162float(sftsh[(size_t)d0 * 64 + lane]);
            float v1 = __bfloat162float(sftsh[(size_t)d1 * 64 + lane]);
            float v2 = __bfloat162float(sftsh[(size_t)d2 * 64 + lane]);
            float v3 = __bfloat162float(sftsh[(size_t)d3 * 64 + lane]);
            float v4 = __bfloat162float(sftsh[(size_t)d4 * 64 + lane]);
            float v5 = __bfloat162float(sftsh[(size_t)d5 * 64 + lane]);
            float v6 = __bfloat162float(sftsh[(size_t)d6 * 64 + lane]);
            float v7 = __bfloat162float(sftsh[(size_t)d7 * 64 + lane]);
            acc = fmaf(c0, v0, acc); acc = fmaf(c1, v1, acc);
            acc = fmaf(c2, v2, acc); acc = fmaf(c3, v3, acc);
            acc = fmaf(c4, v4, acc); acc = fmaf(c5, v5, acc);
            acc = fmaf(c6, v6, acc); acc = fmaf(c7, v7, acc);
        }
    }
    const size_t idx = (size_t)n * 64 + lane;
    float x = out[idx] + acc;
    out[idx] = (x > 0.f) ? x : expm1f(x);
}

extern "C" void kernel_launch(void* const* d_in, const int* in_sizes, int n_in,
                              void* d_out, int out_size, void* d_ws, size_t ws_size,
                              hipStream_t stream) {
    const float* seq  = (const float*)d_in[0];
    const int*   ei   = (const int*)d_in[1];
    const float* Wseq = (const float*)d_in[2];
    const float* wf1  = (const float*)d_in[3];
    const float* bf1  = (const float*)d_in[4];
    const float* wf2  = (const float*)d_in[5];
    const float* bf2  = (const float*)d_in[6];
    const float* bias = (const float*)d_in[7];
    const float* Wres = (const float*)d_in[8];
    const float* bres = (const float*)d_in[9];
    float* out = (float*)d_out;

    // ws layout
    unsigned* pmax1       = (unsigned*)d_ws;
    unsigned* pmax2       = (unsigned*)d_ws + 1;
    float*    psum        = (float*)d_ws + 2;
    unsigned* counts      = (unsigned*)d_ws + 16;
    unsigned* offs        = counts + N_NODES;                      // N_NODES+1
    unsigned* cursor      = offs + N_NODES + 1;
    unsigned short* sDst  = (unsigned short*)(cursor + N_NODES);   // N_EDGES u16
    __hip_bfloat16* sftsh = (__hip_bfloat16*)(sDst + N_EDGES);     // N*64 bf16
    float*    f1          = (float*)(sftsh + (size_t)N_NODES * 64);
    float*    f2          = f1 + N_NODES;
    // total ~11 MB

    k_zero<<<196, 256, 0, stream>>>(pmax1, pmax2, psum, counts);
    k_hist<<<2048, 256, 0, stream>>>(ei, counts);
    k_node<<<3125, 256, 0, stream>>>(seq, Wseq, Wres, wf1, bf1, wf2, bf2, bias,
                                     bres, sftsh, f1, f2, pmax1, pmax2, out);
    k_scan<<<1, SCAN_T, 0, stream>>>(counts, offs, cursor);
    k_placesum<<<2048, 256, 0, stream>>>(ei, f1, f2, pmax1, pmax2, cursor, sDst, psum);
    k_acc<<<12500, 256, 0, stream>>>(offs, sDst, f1, f2, sftsh, pmax1, pmax2, psum, out);
}

// Round 5
// 313.090 us; speedup vs baseline: 1.7562x; 1.2016x over previous
//
#include <hip/hip_runtime.h>
#include <hip/hip_bf16.h>
#include <math.h>

#define N_NODES 50000
#define N_EDGES 1600000
#define IN_CH 128
#define OUT_SZ 64
#define N_TILES 3125   // 50000 / 16

typedef short bf16x8 __attribute__((ext_vector_type(8)));
typedef float f32x4  __attribute__((ext_vector_type(4)));

// monotone f32 -> u32 mapping for atomicMax on floats
__device__ __forceinline__ unsigned fenc(float x) {
    unsigned u = __float_as_uint(x);
    return (u & 0x80000000u) ? ~u : (u | 0x80000000u);
}
__device__ __forceinline__ float fdec(unsigned u) {
    return __uint_as_float((u & 0x80000000u) ? (u & 0x7fffffffu) : ~u);
}

__device__ __forceinline__ short bfbits(float x) {
    union { __hip_bfloat16 h; short s; } u;
    u.h = __float2bfloat16(x);
    return u.s;
}
__device__ __forceinline__ bf16x8 pack8(const float* f) {
    bf16x8 r;
#pragma unroll
    for (int j = 0; j < 8; ++j) r[j] = bfbits(f[j]);
    return r;
}

// ---------------- K0: zero counters + softmax scalars ----------------
__global__ __launch_bounds__(256) void k_zero(unsigned* pmax1, unsigned* pmax2,
                                              float* psum, unsigned* counts) {
    int i = blockIdx.x * 256 + threadIdx.x;
    if (i < N_NODES) counts[i] = 0u;
    if (i == 0) { *pmax1 = 0u; *pmax2 = 0u; *psum = 0.0f; }
}

// ---------------- K0b: src histogram ----------------
__global__ __launch_bounds__(256) void k_hist(const int* __restrict__ ei,
                                              unsigned* __restrict__ counts) {
    int tid = blockIdx.x * 256 + threadIdx.x;
    int stride = gridDim.x * 256;
    for (int e = tid; e < N_EDGES; e += stride)
        atomicAdd(&counts[ei[e]], 1u);
}

// ---------------- K1: node linears via bf16 MFMA ----------------
// 4 waves/block; each wave computes one 16-node tile x all 128 channels.
// B (W_seq||W_res as bf16 fragments) staged in 32 KiB LDS:
//   WL[(ct*4+ks)*64 + lane] = W[c = ct*16+(l&15)][k = ks*32+(l>>4)*8 .. +7]
// A loaded from global f32, packed to bf16 in-register (each element used once).
__global__ __launch_bounds__(256) void k_gemm(
    const float* __restrict__ seq, const float* __restrict__ Wseq,
    const float* __restrict__ Wres, const float* __restrict__ wf1,
    const float* __restrict__ bf1, const float* __restrict__ wf2,
    const float* __restrict__ bf2, const float* __restrict__ bias,
    const float* __restrict__ bres,
    __hip_bfloat16* __restrict__ sftsh, float* __restrict__ f1,
    float* __restrict__ f2, unsigned* pmax1, unsigned* pmax2,
    float* __restrict__ out)
{
    __shared__ bf16x8 WL[2048];     // 32 KiB
    __shared__ float smax[8];
    const int t = threadIdx.x;

#pragma unroll
    for (int j = 0; j < 8; ++j) {
        int idx = t + j * 256;          // 0..2047
        int ct = idx >> 8;              // col tile 0..7
        int ks = (idx >> 6) & 3;        // k step 0..3
        int li = idx & 63;
        int c = ct * 16 + (li & 15);
        int k0 = ks * 32 + (li >> 4) * 8;
        const float* src = (c < 64) ? (Wseq + c * IN_CH + k0)
                                    : (Wres + (c - 64) * IN_CH + k0);
        float tmp[8];
        *(float4*)tmp = *(const float4*)src;
        *(float4*)(tmp + 4) = *(const float4*)(src + 4);
        WL[idx] = pack8(tmp);
    }
    __syncthreads();

    const int l = t & 63;
    const int wv = t >> 6;
    const int tile = blockIdx.x * 4 + wv;
    const bool active = tile < N_TILES;
    float mx1 = -3.0e38f, mx2 = -3.0e38f;

    if (active) {
        const int row = tile * 16 + (l & 15);
        const int kbase = (l >> 4) * 8;
        f32x4 acc[8];
#pragma unroll
        for (int ct = 0; ct < 8; ++ct) acc[ct] = (f32x4){0.f, 0.f, 0.f, 0.f};

#pragma unroll
        for (int ks = 0; ks < 4; ++ks) {
            const float* ap = seq + (size_t)row * IN_CH + ks * 32 + kbase;
            float tmp[8];
            *(float4*)tmp = *(const float4*)ap;
            *(float4*)(tmp + 4) = *(const float4*)(ap + 4);
            bf16x8 af = pack8(tmp);
#pragma unroll
            for (int ct = 0; ct < 8; ++ct)
                acc[ct] = __builtin_amdgcn_mfma_f32_16x16x32_bf16(
                    af, WL[(ct * 4 + ks) * 64 + l], acc[ct], 0, 0, 0);
        }

        // epilogue: C/D layout col = lane&15, row = (lane>>4)*4 + reg
        const int n0 = tile * 16;
        float w1v[4], w2v[4], bb[4];
#pragma unroll
        for (int ct = 0; ct < 4; ++ct) {
            int oc = ct * 16 + (l & 15);
            w1v[ct] = wf1[oc];
            w2v[ct] = wf2[oc];
            bb[ct] = bias[oc] + bres[oc];
        }
        const float B1 = bf1[0], B2 = bf2[0];
#pragma unroll
        for (int r = 0; r < 4; ++r) {
            int node = n0 + (l >> 4) * 4 + r;
            size_t o = (size_t)node * 64 + (l & 15);
#pragma unroll
            for (int ct = 0; ct < 4; ++ct) {
                sftsh[o + ct * 16] = __float2bfloat16(acc[ct][r]);
                out[o + ct * 16] = acc[ct + 4][r] + bb[ct];
            }
            float t1 = acc[0][r] * w1v[0] + acc[1][r] * w1v[1]
                     + acc[2][r] * w1v[2] + acc[3][r] * w1v[3];
            float t2 = acc[0][r] * w2v[0] + acc[1][r] * w2v[1]
                     + acc[2][r] * w2v[2] + acc[3][r] * w2v[3];
#pragma unroll
            for (int m = 8; m; m >>= 1) {
                t1 += __shfl_xor(t1, m);
                t2 += __shfl_xor(t2, m);
            }
            if ((l & 15) == 0) {
                float F1 = t1 + B1, F2 = t2 + B2;
                f1[node] = F1;
                f2[node] = F2;
                mx1 = fmaxf(mx1, F1);
                mx2 = fmaxf(mx2, F2);
            }
        }
    }

    // block-level max -> 2 atomics per block
    mx1 = fmaxf(mx1, __shfl_xor(mx1, 16)); mx1 = fmaxf(mx1, __shfl_xor(mx1, 32));
    mx2 = fmaxf(mx2, __shfl_xor(mx2, 16)); mx2 = fmaxf(mx2, __shfl_xor(mx2, 32));
    if (l == 0) { smax[wv] = mx1; smax[4 + wv] = mx2; }
    __syncthreads();
    if (t == 0) {
        atomicMax(pmax1, fenc(fmaxf(fmaxf(smax[0], smax[1]), fmaxf(smax[2], smax[3]))));
        atomicMax(pmax2, fenc(fmaxf(fmaxf(smax[4], smax[5]), fmaxf(smax[6], smax[7]))));
    }
}

// ---------------- K2: single-block scan (counts -> offs, cursor) ----------------
#define SCAN_T 1024
#define SCAN_PER 49   // 1024*49 = 50176 >= 50000
__global__ __launch_bounds__(SCAN_T) void k_scan(
    const unsigned* __restrict__ counts, unsigned* __restrict__ offs,
    unsigned* __restrict__ cursor)
{
    __shared__ unsigned bs[SCAN_T];
    const int t = threadIdx.x;
    unsigned loc[SCAN_PER];
    unsigned s = 0;
    const int base = t * SCAN_PER;
#pragma unroll
    for (int k = 0; k < SCAN_PER; ++k) {
        int i = base + k;
        unsigned c = (i < N_NODES) ? counts[i] : 0u;
        loc[k] = s;
        s += c;
    }
    bs[t] = s;
    __syncthreads();
    for (int off = 1; off < SCAN_T; off <<= 1) {
        unsigned v = (t >= off) ? bs[t - off] : 0u;
        __syncthreads();
        bs[t] += v;
        __syncthreads();
    }
    unsigned prev = t ? bs[t - 1] : 0u;
#pragma unroll
    for (int k = 0; k < SCAN_PER; ++k) {
        int i = base + k;
        if (i < N_NODES) {
            unsigned o = prev + loc[k];
            offs[i] = o;
            cursor[i] = o;
        }
    }
    if (t == SCAN_T - 1) offs[N_NODES] = bs[SCAN_T - 1];
}

// ---------------- K3: place dst (u16) into src-sorted order + sum exp ----------------
__global__ __launch_bounds__(256) void k_placesum(
    const int* __restrict__ ei, const float* __restrict__ f1,
    const float* __restrict__ f2, const unsigned* __restrict__ pmax1,
    const unsigned* __restrict__ pmax2, unsigned* __restrict__ cursor,
    unsigned short* __restrict__ sDst, float* psum)
{
    float M = fdec(*pmax1) + fdec(*pmax2);
    M = (M > 0.f) ? M : 0.01f * M;          // LRelu of upper bound: valid shift constant
    int tid = blockIdx.x * 256 + threadIdx.x;
    int stride = gridDim.x * 256;
    float ls = 0.f;
    for (int e = tid; e < N_EDGES; e += stride) {
        int src = ei[e];
        int dst = ei[N_EDGES + e];
        float x = f1[src] + f2[dst];
        x = (x > 0.f) ? x : 0.01f * x;
        ls += __expf(x - M);
        unsigned pos = atomicAdd(&cursor[src], 1u);
        sDst[pos] = (unsigned short)dst;
    }
#pragma unroll
    for (int off = 32; off; off >>= 1) ls += __shfl_xor(ls, off);
    __shared__ float red[4];
    if ((threadIdx.x & 63) == 0) red[threadIdx.x >> 6] = ls;
    __syncthreads();
    if (threadIdx.x == 0) {
        ls = red[0] + red[1] + red[2] + red[3];
        unsafeAtomicAdd(psum, ls);
    }
}

// ---------------- K4: per-node accumulate + ELU, 8-deep pipelined gathers ----------------
__global__ __launch_bounds__(256) void k_acc(
    const unsigned* __restrict__ offs, const unsigned short* __restrict__ sDst,
    const float* __restrict__ f1, const float* __restrict__ f2,
    const __hip_bfloat16* __restrict__ sftsh, const unsigned* __restrict__ pmax1,
    const unsigned* __restrict__ pmax2, const float* __restrict__ psum,
    float* __restrict__ out)
{
    const int lane = threadIdx.x & 63;
    const int n = (blockIdx.x * 256 + threadIdx.x) >> 6;
    if (n >= N_NODES) return;
    float M = fdec(*pmax1) + fdec(*pmax2);
    M = (M > 0.f) ? M : 0.01f * M;
    const float inv = 1.0f / (*psum);
    const unsigned b = offs[n];
    const unsigned e = offs[n + 1];
    const float f1n = f1[n];

    float acc = 0.f;
    for (unsigned e0 = b; e0 < e; e0 += 64) {
        const int cnt = (int)min(64u, e - e0);
        int dst = 0;
        float coef = 0.f;               // lanes >= cnt contribute 0
        if (lane < cnt) {
            dst = (int)sDst[e0 + lane];
            float x = f1n + f2[dst];
            x = (x > 0.f) ? x : 0.01f * x;
            coef = __expf(x - M) * inv;
        }
        const int nb = (cnt + 7) & ~7;  // ragged tail handled by coef==0 lanes
        for (int j = 0; j < nb; j += 8) {
            int d0 = __shfl(dst, j);     float c0 = __shfl(coef, j);
            int d1 = __shfl(dst, j + 1); float c1 = __shfl(coef, j + 1);
            int d2 = __shfl(dst, j + 2); float c2 = __shfl(coef, j + 2);
            int d3 = __shfl(dst, j + 3); float c3 = __shfl(coef, j + 3);
            int d4 = __shfl(dst, j + 4); float c4 = __shfl(coef, j + 4);
            int d5 = __shfl(dst, j + 5); float c5 = __shfl(coef, j + 5);
            int d6 = __shfl(dst, j + 6); float c6 = __shfl(coef, j + 6);
            int d7 = __shfl(dst, j + 7); float c7 = __shfl(coef, j + 7);
            float v0 = __bfloat162float(sftsh[(size_t)d0 * 64 + lane]);
            float v1 = __bfloat162float(sftsh[(size_t)d1 * 64 + lane]);
            float v2 = __bfloat162float(sftsh[(size_t)d2 * 64 + lane]);
            float v3 = __bfloat162float(sftsh[(size_t)d3 * 64 + lane]);
            float v4 = __bfloat162float(sftsh[(size_t)d4 * 64 + lane]);
            float v5 = __bfloat162float(sftsh[(size_t)d5 * 64 + lane]);
            float v6 = __bfloat162float(sftsh[(size_t)d6 * 64 + lane]);
            float v7 = __bfloat162float(sftsh[(size_t)d7 * 64 + lane]);
            acc = fmaf(c0, v0, acc); acc = fmaf(c1, v1, acc);
            acc = fmaf(c2, v2, acc); acc = fmaf(c3, v3, acc);
            acc = fmaf(c4, v4, acc); acc = fmaf(c5, v5, acc);
            acc = fmaf(c6, v6, acc); acc = fmaf(c7, v7, acc);
        }
    }
    const size_t idx = (size_t)n * 64 + lane;
    float x = out[idx] + acc;
    out[idx] = (x > 0.f) ? x : expm1f(x);
}

extern "C" void kernel_launch(void* const* d_in, const int* in_sizes, int n_in,
                              void* d_out, int out_size, void* d_ws, size_t ws_size,
                              hipStream_t stream) {
    const float* seq  = (const float*)d_in[0];
    const int*   ei   = (const int*)d_in[1];
    const float* Wseq = (const float*)d_in[2];
    const float* wf1  = (const float*)d_in[3];
    const float* bf1  = (const float*)d_in[4];
    const float* wf2  = (const float*)d_in[5];
    const float* bf2  = (const float*)d_in[6];
    const float* bias = (const float*)d_in[7];
    const float* Wres = (const float*)d_in[8];
    const float* bres = (const float*)d_in[9];
    float* out = (float*)d_out;

    // ws layout
    unsigned* pmax1       = (unsigned*)d_ws;
    unsigned* pmax2       = (unsigned*)d_ws + 1;
    float*    psum        = (float*)d_ws + 2;
    unsigned* counts      = (unsigned*)d_ws + 16;
    unsigned* offs        = counts + N_NODES;                      // N_NODES+1
    unsigned* cursor      = offs + N_NODES + 1;
    unsigned short* sDst  = (unsigned short*)(cursor + N_NODES);   // N_EDGES u16
    __hip_bfloat16* sftsh = (__hip_bfloat16*)(sDst + N_EDGES);     // N*64 bf16
    float*    f1          = (float*)(sftsh + (size_t)N_NODES * 64);
    float*    f2          = f1 + N_NODES;
    // total ~11 MB

    k_zero<<<196, 256, 0, stream>>>(pmax1, pmax2, psum, counts);
    k_hist<<<2048, 256, 0, stream>>>(ei, counts);
    k_gemm<<<782, 256, 0, stream>>>(seq, Wseq, Wres, wf1, bf1, wf2, bf2, bias,
                                    bres, sftsh, f1, f2, pmax1, pmax2, out);
    k_scan<<<1, SCAN_T, 0, stream>>>(counts, offs, cursor);
    k_placesum<<<2048, 256, 0, stream>>>(ei, f1, f2, pmax1, pmax2, cursor, sDst, psum);
    k_acc<<<12500, 256, 0, stream>>>(offs, sDst, f1, f2, sftsh, pmax1, pmax2, psum, out);
}